// Round 9
// baseline (368.605 us; speedup 1.0000x reference)
//
#include <hip/hip_runtime.h>
#include <math.h>

#define CH    64
#define WW    192
#define HH    192
#define HWSZ  (192*192)
#define KK    49
#define ROWP  68   // padded fp32 LDS row (dwords)
#define SROW  72   // bf16 row stride in shorts (144B)
#define C3ROW 72   // conv3 staged px stride (shorts)
#define OROW  136  // k_out staged px stride (shorts, 128ch + 8 pad)

typedef __attribute__((ext_vector_type(8))) short s16x8;   // 8 bf16 = 4 VGPR
typedef __attribute__((ext_vector_type(4))) float f32x4;

__device__ __forceinline__ unsigned short f2bf(float f) {
    union { float f; unsigned u; } v; v.f = f;
    unsigned u = v.u + 0x7FFFu + ((v.u >> 16) & 1u);   // RNE
    return (unsigned short)(u >> 16);
}

// pack two floats to bf16x2 (round-half-up): 2 adds + 1 v_perm
__device__ __forceinline__ unsigned pkbf(float lo, float hi) {
    return __builtin_amdgcn_perm(__float_as_uint(hi) + 0x8000u,
                                 __float_as_uint(lo) + 0x8000u, 0x07060302u);
}

// ---------------------------------------------------------------------------
// k_prep (grid 49 x 256): krT + A-fragment packs (wA, w2A, wpoA, wpiA)
// ---------------------------------------------------------------------------
__device__ const float c_cos8[8] = {
    1.f, 0.70710678118654752f, 0.f, -0.70710678118654752f,
   -1.f, -0.70710678118654752f, 0.f, 0.70710678118654752f };

__global__ __launch_bounds__(256) void k_prep(
    const float* __restrict__ fw,   // [64,1,1,8,5]
    const float* __restrict__ wd,   // [64,64,7,7]
    const float* __restrict__ w2,   // [64,64,3,3]
    const float* __restrict__ wc1,  // [64,64,1,1]
    const float* __restrict__ wpo,  // [128,128]
    const float* __restrict__ wpi,  // [64,64]
    float* __restrict__ krT,        // [64 uv][64 c]
    short* __restrict__ wA,         // [49*8*512]
    short* __restrict__ w2A,        // [9*8*512]
    short* __restrict__ wpoA,       // [32*512]
    short* __restrict__ wpiA)       // [8*512]
{
    int tid = blockIdx.x * blockDim.x + threadIdx.x;
    int nt  = gridDim.x * blockDim.x;
    for (int t = tid; t < 64 * 64; t += nt) {
        int uv = t >> 6, c = t & 63;
        int u = uv >> 3, v = uv & 7;
        float acc = 0.f;
        for (int ky = 0; ky < 8; ky++)
            for (int kx = 0; kx < 8; kx++) {
                float wv = (kx <= 4) ? fw[c * 40 + ky * 5 + kx]
                                     : fw[c * 40 + ((8 - ky) & 7) * 5 + (8 - kx)];
                acc += wv * c_cos8[(ky * u + kx * v) & 7];
            }
        krT[uv * 64 + c] = acc * (1.f / 64.f);
    }
    for (int t = tid; t < 9 * 4096; t += nt) {
        int tap = t / 4096, rem = t & 4095;
        int o = rem >> 6, c = rem & 63;
        float v = w2[(o * 64 + c) * 9 + tap];
        int fi = tap * 8 + (o >> 4) * 2 + (c >> 5);
        int ln = ((c >> 3) & 3) * 16 + (o & 15);
        w2A[fi * 512 + ln * 8 + (c & 7)] = (short)f2bf(v);
    }
    for (int t = tid; t < 128 * 128; t += nt) {
        int o = t >> 7, c = t & 127;
        int fi = (o >> 4) * 4 + (c >> 5);
        int ln = ((c >> 3) & 3) * 16 + (o & 15);
        wpoA[fi * 512 + ln * 8 + (c & 7)] = (short)f2bf(wpo[t]);
    }
    for (int t = tid; t < 64 * 64; t += nt) {
        int o = t >> 6, c = t & 63;
        int fi = (o >> 4) * 2 + (c >> 5);
        int ln = ((c >> 3) & 3) * 16 + (o & 15);
        wpiA[fi * 512 + ln * 8 + (c & 7)] = (short)f2bf(wpi[t]);
    }

    // ---- fold wc1 @ wd + pack: one block per tap k ----
    __shared__ float wdk [64 * ROWP];
    __shared__ float wc1s[64 * ROWP];
    int k = blockIdx.x;
    int t = threadIdx.x;
#pragma unroll
    for (int r = 0; r < 16; r++) {
        int idx = t + r * 256;
        int o = idx >> 6, c = idx & 63;
        wdk [o * ROWP + c] = wd[(o * 64 + c) * KK + k];
        wc1s[o * ROWP + c] = wc1[o * 64 + c];
    }
    __syncthreads();

    int ot = (t >> 4) * 4, cb = (t & 15) * 4;
    float a[4][4];
#pragma unroll
    for (int i = 0; i < 4; i++)
#pragma unroll
        for (int j = 0; j < 4; j++) a[i][j] = 0.f;
    for (int o = 0; o < 64; o++) {
        float wv_[4], sv_[4];
#pragma unroll
        for (int i = 0; i < 4; i++) wv_[i] = wc1s[(ot + i) * ROWP + o];
#pragma unroll
        for (int j = 0; j < 4; j++) sv_[j] = wdk[o * ROWP + cb + j];
#pragma unroll
        for (int i = 0; i < 4; i++)
#pragma unroll
            for (int j = 0; j < 4; j++) a[i][j] += wv_[i] * sv_[j];
    }
#pragma unroll
    for (int i = 0; i < 4; i++)
#pragma unroll
        for (int j = 0; j < 4; j++) {
            int o2 = ot + i, c = cb + j;
            int tt = o2 >> 4, m = o2 & 15;
            int kt = c >> 5, q = (c >> 3) & 3, jj = c & 7;
            int ln = q * 16 + m;
            wA[(k * 8 + tt * 2 + kt) * 512 + ln * 8 + jj] = (short)f2bf(a[i][j]);
        }
}

// ---------------------------------------------------------------------------
// k_trans: enc [c][p] -> encP [p][c]
// ---------------------------------------------------------------------------
__global__ __launch_bounds__(256) void k_trans(
    const float* __restrict__ enc, float* __restrict__ encP)
{
    __shared__ float s[64 * 65];
    int t = threadIdx.x;
    int base = blockIdx.x * 64;
#pragma unroll
    for (int r = 0; r < 16; r++) {
        int idx = t + r * 256;
        int p = idx & 63, c = idx >> 6;
        s[p * 65 + c] = enc[c * HWSZ + base + p];
    }
    __syncthreads();
#pragma unroll
    for (int r = 0; r < 16; r++) {
        int idx = t + r * 256;
        int c = idx & 63, p = idx >> 6;
        encP[(base + p) * 64 + c] = s[p * 65 + c];
    }
}

// ---------------------------------------------------------------------------
// k_deform: MFMA deformable conv, K-split across waves, NO LDS bounce:
// sampling role == B-fragment role. Lane (q,n) gathers+blends exactly the
// 16 channels (q*8..q*8+7, 32+q*8..+7) of pixel n that its MFMA B operand
// holds, packs straight into b0/b1 registers. Per tap: 16 vmem + blend +
// pack + 8 MFMA -- no ds ops, no bank conflicts. LDS = 10 KB reduction only.
// ---------------------------------------------------------------------------
#define REDW 20   // reduction row stride (floats): 80B, 16B-aligned

__global__ __launch_bounds__(256) void k_deform(
    const float* __restrict__ encP, const float* __restrict__ off,
    const float* __restrict__ msk, const short* __restrict__ wA,
    float* __restrict__ rev)
{
    __shared__ __align__(16) float red[2 * 64 * REDW]; // 10240 B

    int t = threadIdx.x;
    int lane = t & 63, w = t >> 6;
    int b = blockIdx.x;
    int xcd = b & 7, blk = b >> 3;          // 288 strips per xcd band
    int gy  = xcd * 24 + blk / 12;
    int gx0 = (blk % 12) * 16;

    int n = lane & 15, q = lane >> 4;
    int sgx  = gx0 + n;
    int gp_s = gy * WW + sgx;               // per-pixel (4-lane broadcast)
    int cq   = q * 8;                       // channel base for b0; +32 for b1

    f32x4 acc[4];
#pragma unroll
    for (int ot = 0; ot < 4; ot++) acc[ot] = (f32x4){0.f, 0.f, 0.f, 0.f};

    int kstart = (w == 0) ? 0 : 13 + (w - 1) * 12;
    int kend   = (w == 0) ? 13 : kstart + 12;

    float dy = off[(2 * kstart) * HWSZ + gp_s];
    float dx = off[(2 * kstart + 1) * HWSZ + gp_s];
    float mm = msk[kstart * HWSZ + gp_s];

#pragma unroll 1
    for (int k = kstart; k < kend; k++) {
        int ky = k / 7, kx = k % 7;
        float y = (float)(gy  - 3 + ky) + dy;
        float x = (float)(sgx - 3 + kx) + dx;
        float y0f = floorf(y), x0f = floorf(x);
        float wy = y - y0f, wx = x - x0f;
        int iy0 = (int)y0f, ix0 = (int)x0f;
        int iy1 = iy0 + 1, ix1 = ix0 + 1;
        bool vy0 = (iy0 >= 0) & (iy0 < HH);
        bool vy1 = (iy1 >= 0) & (iy1 < HH);
        bool vx0 = (ix0 >= 0) & (ix0 < WW);
        bool vx1 = (ix1 >= 0) & (ix1 < WW);
        int iy0c = min(max(iy0, 0), HH - 1), iy1c = min(max(iy1, 0), HH - 1);
        int ix0c = min(max(ix0, 0), WW - 1), ix1c = min(max(ix1, 0), WW - 1);
        float a00 = (vy0 & vx0) ? (1.f - wy) * (1.f - wx) * mm : 0.f;
        float a01 = (vy0 & vx1) ? (1.f - wy) * wx * mm : 0.f;
        float a10 = (vy1 & vx0) ? wy * (1.f - wx) * mm : 0.f;
        float a11 = (vy1 & vx1) ? wy * wx * mm : 0.f;

        const float* base00 = encP + (iy0c * WW + ix0c) * 64 + cq;
        const float* base01 = encP + (iy0c * WW + ix1c) * 64 + cq;
        const float* base10 = encP + (iy1c * WW + ix0c) * 64 + cq;
        const float* base11 = encP + (iy1c * WW + ix1c) * 64 + cq;
        // per corner: ch [cq,cq+8) and [32+cq, 32+cq+8)  -> 4x float4
        float4 v00[4], v01[4], v10[4], v11[4];
#pragma unroll
        for (int h = 0; h < 2; h++) {
            v00[2*h]   = *(const float4*)(base00 + 32*h);
            v00[2*h+1] = *(const float4*)(base00 + 32*h + 4);
            v01[2*h]   = *(const float4*)(base01 + 32*h);
            v01[2*h+1] = *(const float4*)(base01 + 32*h + 4);
            v10[2*h]   = *(const float4*)(base10 + 32*h);
            v10[2*h+1] = *(const float4*)(base10 + 32*h + 4);
            v11[2*h]   = *(const float4*)(base11 + 32*h);
            v11[2*h+1] = *(const float4*)(base11 + 32*h + 4);
        }

        // prefetch next-tap offsets
        float dyn = 0.f, dxn = 0.f, mmn = 0.f;
        if (k + 1 < kend) {
            dyn = off[(2 * k + 2) * HWSZ + gp_s];
            dxn = off[(2 * k + 3) * HWSZ + gp_s];
            mmn = msk[(k + 1) * HWSZ + gp_s];
        }

        // A-frag loads (L2-hot, independent of samples)
        s16x8 af[8];
#pragma unroll
        for (int f = 0; f < 8; f++)
            af[f] = *(const s16x8*)&wA[(k * 8 + f) * 512 + lane * 8];

        // blend + pack directly into B fragments (no LDS)
        union { unsigned u[4]; s16x8 v; } bu[2];
#pragma unroll
        for (int h = 0; h < 2; h++)
#pragma unroll
            for (int i = 0; i < 2; i++) {
                int idx = 2 * h + i;
                float f0 = a00*v00[idx].x + a01*v01[idx].x + a10*v10[idx].x + a11*v11[idx].x;
                float f1 = a00*v00[idx].y + a01*v01[idx].y + a10*v10[idx].y + a11*v11[idx].y;
                float f2 = a00*v00[idx].z + a01*v01[idx].z + a10*v10[idx].z + a11*v11[idx].z;
                float f3 = a00*v00[idx].w + a01*v01[idx].w + a10*v10[idx].w + a11*v11[idx].w;
                bu[h].u[2*i]   = pkbf(f0, f1);
                bu[h].u[2*i+1] = pkbf(f2, f3);
            }

#pragma unroll
        for (int ot = 0; ot < 4; ot++) {
            acc[ot] = __builtin_amdgcn_mfma_f32_16x16x32_bf16(af[ot * 2],     bu[0].v, acc[ot], 0, 0, 0);
            acc[ot] = __builtin_amdgcn_mfma_f32_16x16x32_bf16(af[ot * 2 + 1], bu[1].v, acc[ot], 0, 0, 0);
        }

        dy = dyn; dx = dxn; mm = mmn;
    }

    // two-phase tree reduction (2-slot buffer)
    if (w >= 2) {
        float* rp = &red[((w - 2) * 64 + lane) * REDW];
#pragma unroll
        for (int ot = 0; ot < 4; ot++)
            *(float4*)&rp[ot * 4] = make_float4(acc[ot][0], acc[ot][1], acc[ot][2], acc[ot][3]);
    }
    __syncthreads();
    if (w < 2) {
        const float* rp = &red[(w * 64 + lane) * REDW];
#pragma unroll
        for (int ot = 0; ot < 4; ot++) {
            float4 v = *(const float4*)&rp[ot * 4];
            acc[ot][0] += v.x; acc[ot][1] += v.y;
            acc[ot][2] += v.z; acc[ot][3] += v.w;
        }
    }
    __syncthreads();
    if (w == 1) {
        float* rp = &red[lane * REDW];
#pragma unroll
        for (int ot = 0; ot < 4; ot++)
            *(float4*)&rp[ot * 4] = make_float4(acc[ot][0], acc[ot][1], acc[ot][2], acc[ot][3]);
    }
    __syncthreads();
    if (w == 0) {
        const float* rp = &red[lane * REDW];
#pragma unroll
        for (int ot = 0; ot < 4; ot++) {
            float4 v = *(const float4*)&rp[ot * 4];
            acc[ot][0] += v.x; acc[ot][1] += v.y;
            acc[ot][2] += v.z; acc[ot][3] += v.w;
        }
        int gp_m = gy * WW + gx0 + n;
#pragma unroll
        for (int ot = 0; ot < 4; ot++) {
            float4 rv = make_float4(acc[ot][0], acc[ot][1], acc[ot][2], acc[ot][3]);
            *(float4*)&rev[gp_m * 64 + ot * 16 + q * 4] = rv;
        }
    }
}

// ---------------------------------------------------------------------------
// k_fft: per 8x8 patch: proj_in via MFMA bf16, then circular conv (fp32).
// ---------------------------------------------------------------------------
__global__ __launch_bounds__(256) void k_fft(
    const float* __restrict__ encPg, const short* __restrict__ wpiA,
    const float* __restrict__ krT, float* __restrict__ e1)
{
    __shared__ __align__(16) short sbf[64 * SROW];   // bf16 enc [px][c]
    __shared__ __align__(16) float e0[64 * ROWP];    // fp32 [px][o]
    int t = threadIdx.x;
    int pbx = blockIdx.x % 24, pby = blockIdx.x / 24;
    int gx0 = pbx * 8, gy0 = pby * 8;

#pragma unroll
    for (int r = 0; r < 4; r++) {
        int idx = t + r * 256;
        int px = idx >> 4, g = idx & 15;
        int gy = gy0 + (px >> 3), gx = gx0 + (px & 7);
        float4 v = *(const float4*)&encPg[(gy * WW + gx) * 64 + g * 4];
        *(uint2*)&sbf[px * SROW + g * 4] = make_uint2(pkbf(v.x, v.y), pkbf(v.z, v.w));
    }
    __syncthreads();

    int lane = t & 63, w = t >> 6;
    int n = lane & 15, q = lane >> 4;
    s16x8 a0 = *(const s16x8*)&wpiA[(w * 2 + 0) * 512 + lane * 8];
    s16x8 a1 = *(const s16x8*)&wpiA[(w * 2 + 1) * 512 + lane * 8];
#pragma unroll
    for (int j = 0; j < 4; j++) {
        s16x8 b0 = *(const s16x8*)&sbf[(j * 16 + n) * SROW +  0 + q * 8];
        s16x8 b1 = *(const s16x8*)&sbf[(j * 16 + n) * SROW + 32 + q * 8];
        f32x4 acc = {0.f, 0.f, 0.f, 0.f};
        acc = __builtin_amdgcn_mfma_f32_16x16x32_bf16(a0, b0, acc, 0, 0, 0);
        acc = __builtin_amdgcn_mfma_f32_16x16x32_bf16(a1, b1, acc, 0, 0, 0);
#pragma unroll
        for (int r = 0; r < 4; r++)
            e0[(j * 16 + n) * ROWP + w * 16 + q * 4 + r] = acc[r];
    }
    __syncthreads();

    int o = t & 63;
    int yb = t >> 6;
#pragma unroll
    for (int yy = 0; yy < 2; yy++) {
        int y = yb + yy * 4;
        float outr[8];
#pragma unroll
        for (int x = 0; x < 8; x++) outr[x] = 0.f;
#pragma unroll
        for (int u = 0; u < 8; u++) {
            int ry = (y - u + 8) & 7;
            float row[8];
#pragma unroll
            for (int rx = 0; rx < 8; rx++)
                row[rx] = e0[(ry * 8 + rx) * ROWP + o];
#pragma unroll
            for (int v = 0; v < 8; v++) {
                float kv = krT[(u * 8 + v) * 64 + o];
#pragma unroll
                for (int x = 0; x < 8; x++)
                    outr[x] += kv * row[(x - v + 8) & 7];
            }
        }
        int gy = gy0 + y;
#pragma unroll
        for (int x = 0; x < 8; x++)
            e1[(gy * WW + gx0 + x) * 64 + o] = outr[x];
    }
}

// ---------------------------------------------------------------------------
// k_c3out: fused conv3x3(e1+rev) -> [.,dec] -> proj_out -> SimpleGate.
// ---------------------------------------------------------------------------
__global__ __launch_bounds__(256) void k_c3out(
    const float* __restrict__ e1, const float* __restrict__ rev,
    const short* __restrict__ w2A, const float* __restrict__ dec,
    const short* __restrict__ wpoA, float* __restrict__ out)
{
    __shared__ __align__(16) short sm[4][54 * C3ROW];  // per-wave: 3 rows x 18 px
    int t = threadIdx.x;
    int lane = t & 63, w = t >> 6;
    int b = blockIdx.x;
    int xcd = b & 7, blk = b >> 3;
    int gy  = xcd * 24 + blk / 3;
    int gx0 = (blk % 3) * 64 + w * 16;
    short* smw = &sm[w][0];
    int n = lane & 15, q = lane >> 4;

    for (int r = 0; r < 14; r++) {
        int u = lane + r * 64;
        if (u < 864) {
            int rp = u >> 4, g = u & 15;
            int row = rp / 18, pxl = rp - row * 18;
            int gyy = gy + row - 1, gxx = gx0 + pxl - 1;
            float4 v = make_float4(0.f, 0.f, 0.f, 0.f);
            if (gyy >= 0 && gyy < HH && gxx >= 0 && gxx < WW) {
                int gp = (gyy * WW + gxx) * 64 + g * 4;
                float4 va = *(const float4*)&e1[gp];
                float4 vb = *(const float4*)&rev[gp];
                v.x = va.x + vb.x; v.y = va.y + vb.y;
                v.z = va.z + vb.z; v.w = va.w + vb.w;
            }
            *(uint2*)&smw[rp * C3ROW + g * 4] = make_uint2(pkbf(v.x, v.y), pkbf(v.z, v.w));
        }
    }

    f32x4 acc[4];
#pragma unroll
    for (int ot = 0; ot < 4; ot++) acc[ot] = (f32x4){0.f, 0.f, 0.f, 0.f};

#pragma unroll 1
    for (int tap = 0; tap < 9; tap++) {
        int dy = tap / 3, dx = tap - dy * 3;
        int rp = dy * 18 + n + dx;
        s16x8 b0 = *(const s16x8*)&smw[rp * C3ROW +  0 + q * 8];
        s16x8 b1 = *(const s16x8*)&smw[rp * C3ROW + 32 + q * 8];
#pragma unroll
        for (int ot = 0; ot < 4; ot++) {
            s16x8 a0 = *(const s16x8*)&w2A[(tap * 8 + ot * 2 + 0) * 512 + lane * 8];
            s16x8 a1 = *(const s16x8*)&w2A[(tap * 8 + ot * 2 + 1) * 512 + lane * 8];
            acc[ot] = __builtin_amdgcn_mfma_f32_16x16x32_bf16(a0, b0, acc[ot], 0, 0, 0);
            acc[ot] = __builtin_amdgcn_mfma_f32_16x16x32_bf16(a1, b1, acc[ot], 0, 0, 0);
        }
    }

    // fused proj_out: stage e3 (C-layout regs) + dec into B-frag rows
#pragma unroll
    for (int ot = 0; ot < 4; ot++) {
        unsigned lo = pkbf(acc[ot][0], acc[ot][1]);
        unsigned hi = pkbf(acc[ot][2], acc[ot][3]);
        *(uint2*)&smw[n * OROW + ot * 16 + q * 4] = make_uint2(lo, hi);
    }
    {
        int gp = gy * WW + gx0 + n;
        unsigned pk[8];
#pragma unroll
        for (int i = 0; i < 8; i++) {
            float va = dec[(q * 16 + 2 * i)     * HWSZ + gp];
            float vb = dec[(q * 16 + 2 * i + 1) * HWSZ + gp];
            pk[i] = pkbf(va, vb);
        }
        *(uint4*)&smw[n * OROW + 64 + q * 16]     = make_uint4(pk[0], pk[1], pk[2], pk[3]);
        *(uint4*)&smw[n * OROW + 64 + q * 16 + 8] = make_uint4(pk[4], pk[5], pk[6], pk[7]);
    }

    f32x4 go[8];
#pragma unroll
    for (int ot = 0; ot < 8; ot++) go[ot] = (f32x4){0.f, 0.f, 0.f, 0.f};

#pragma unroll 1
    for (int kt = 0; kt < 4; kt++) {
        s16x8 bb = *(const s16x8*)&smw[n * OROW + kt * 32 + q * 8];
#pragma unroll
        for (int ot = 0; ot < 8; ot++) {
            s16x8 aa = *(const s16x8*)&wpoA[(ot * 4 + kt) * 512 + lane * 8];
            go[ot] = __builtin_amdgcn_mfma_f32_16x16x32_bf16(aa, bb, go[ot], 0, 0, 0);
        }
    }

    int gp = gy * WW + gx0 + n;
#pragma unroll
    for (int ot = 0; ot < 4; ot++)
#pragma unroll
        for (int r = 0; r < 4; r++)
            out[(ot * 16 + q * 4 + r) * HWSZ + gp] = go[ot][r] * go[ot + 4][r];
}

// ---------------------------------------------------------------------------
extern "C" void kernel_launch(void* const* d_in, const int* in_sizes, int n_in,
                              void* d_out, int out_size, void* d_ws, size_t ws_size,
                              hipStream_t stream)
{
    const float* enc  = (const float*)d_in[0];
    const float* dec  = (const float*)d_in[1];
    const float* ioff = (const float*)d_in[2];
    const float* iwt  = (const float*)d_in[3];
    const float* wpi  = (const float*)d_in[4];
    const float* fw   = (const float*)d_in[5];
    const float* wpo  = (const float*)d_in[6];
    const float* wd   = (const float*)d_in[7];
    const float* wc1  = (const float*)d_in[8];
    const float* wc2  = (const float*)d_in[9];
    float* out = (float*)d_out;
    float* ws  = (float*)d_ws;

    float* krT  = ws;                       //    4096
    float* rev  = ws + 4096;                // 2359296  [px][64]
    float* e1   = ws + 2363392;             // 2359296  [px][64]
    float* encP = ws + 4722688;             // 2359296  [px][64]
    short* wA   = (short*)(ws + 7081984);   // 200704 bf16
    short* w2A  = (short*)(ws + 7182336);   //  36864 bf16
    short* wpoA = (short*)(ws + 7200768);   //  16384 bf16
    short* wpiA = (short*)(ws + 7208960);   //   4096 bf16

    hipLaunchKernelGGL(k_prep,   dim3(49),   dim3(256), 0, stream,
                       fw, wd, wc2, wc1, wpo, wpi, krT, wA, w2A, wpoA, wpiA);
    hipLaunchKernelGGL(k_trans,  dim3(576),  dim3(256), 0, stream, enc, encP);
    hipLaunchKernelGGL(k_deform, dim3(2304), dim3(256), 0, stream, encP, ioff, iwt, wA, rev);
    hipLaunchKernelGGL(k_fft,    dim3(576),  dim3(256), 0, stream, encP, wpiA, krT, e1);
    hipLaunchKernelGGL(k_c3out,  dim3(576),  dim3(256), 0, stream, e1, rev, w2A, dec, wpoA, out);
}

// Round 10
// 295.963 us; speedup vs baseline: 1.2454x; 1.2454x over previous
//
#include <hip/hip_runtime.h>
#include <math.h>

#define CH    64
#define WW    192
#define HH    192
#define HWSZ  (192*192)
#define KK    49
#define ROWP  68   // padded fp32 LDS row (dwords)
#define SROW  72   // bf16 row stride in shorts (144B)
#define C3ROW 72   // conv3 staged px stride (shorts)
#define OROW  136  // k_out staged px stride (shorts, 128ch + 8 pad)

typedef __attribute__((ext_vector_type(8))) short s16x8;   // 8 bf16 = 4 VGPR
typedef __attribute__((ext_vector_type(4))) float f32x4;

__device__ __forceinline__ unsigned short f2bf(float f) {
    union { float f; unsigned u; } v; v.f = f;
    unsigned u = v.u + 0x7FFFu + ((v.u >> 16) & 1u);   // RNE
    return (unsigned short)(u >> 16);
}

// pack two floats to bf16x2 (round-half-up): 2 adds + 1 v_perm
__device__ __forceinline__ unsigned pkbf(float lo, float hi) {
    return __builtin_amdgcn_perm(__float_as_uint(hi) + 0x8000u,
                                 __float_as_uint(lo) + 0x8000u, 0x07060302u);
}

// ---------------------------------------------------------------------------
// k_prep (grid 49 x 256): krT + A-fragment packs (wA, w2A, wpoA, wpiA)
// ---------------------------------------------------------------------------
__device__ const float c_cos8[8] = {
    1.f, 0.70710678118654752f, 0.f, -0.70710678118654752f,
   -1.f, -0.70710678118654752f, 0.f, 0.70710678118654752f };

__global__ __launch_bounds__(256) void k_prep(
    const float* __restrict__ fw,   // [64,1,1,8,5]
    const float* __restrict__ wd,   // [64,64,7,7]
    const float* __restrict__ w2,   // [64,64,3,3]
    const float* __restrict__ wc1,  // [64,64,1,1]
    const float* __restrict__ wpo,  // [128,128]
    const float* __restrict__ wpi,  // [64,64]
    float* __restrict__ krT,        // [64 uv][64 c]
    short* __restrict__ wA,         // [49*8*512]
    short* __restrict__ w2A,        // [9*8*512]
    short* __restrict__ wpoA,       // [32*512]
    short* __restrict__ wpiA)       // [8*512]
{
    int tid = blockIdx.x * blockDim.x + threadIdx.x;
    int nt  = gridDim.x * blockDim.x;
    for (int t = tid; t < 64 * 64; t += nt) {
        int uv = t >> 6, c = t & 63;
        int u = uv >> 3, v = uv & 7;
        float acc = 0.f;
        for (int ky = 0; ky < 8; ky++)
            for (int kx = 0; kx < 8; kx++) {
                float wv = (kx <= 4) ? fw[c * 40 + ky * 5 + kx]
                                     : fw[c * 40 + ((8 - ky) & 7) * 5 + (8 - kx)];
                acc += wv * c_cos8[(ky * u + kx * v) & 7];
            }
        krT[uv * 64 + c] = acc * (1.f / 64.f);
    }
    for (int t = tid; t < 9 * 4096; t += nt) {
        int tap = t / 4096, rem = t & 4095;
        int o = rem >> 6, c = rem & 63;
        float v = w2[(o * 64 + c) * 9 + tap];
        int fi = tap * 8 + (o >> 4) * 2 + (c >> 5);
        int ln = ((c >> 3) & 3) * 16 + (o & 15);
        w2A[fi * 512 + ln * 8 + (c & 7)] = (short)f2bf(v);
    }
    for (int t = tid; t < 128 * 128; t += nt) {
        int o = t >> 7, c = t & 127;
        int fi = (o >> 4) * 4 + (c >> 5);
        int ln = ((c >> 3) & 3) * 16 + (o & 15);
        wpoA[fi * 512 + ln * 8 + (c & 7)] = (short)f2bf(wpo[t]);
    }
    for (int t = tid; t < 64 * 64; t += nt) {
        int o = t >> 6, c = t & 63;
        int fi = (o >> 4) * 2 + (c >> 5);
        int ln = ((c >> 3) & 3) * 16 + (o & 15);
        wpiA[fi * 512 + ln * 8 + (c & 7)] = (short)f2bf(wpi[t]);
    }

    // ---- fold wc1 @ wd + pack: one block per tap k ----
    __shared__ float wdk [64 * ROWP];
    __shared__ float wc1s[64 * ROWP];
    int k = blockIdx.x;
    int t = threadIdx.x;
#pragma unroll
    for (int r = 0; r < 16; r++) {
        int idx = t + r * 256;
        int o = idx >> 6, c = idx & 63;
        wdk [o * ROWP + c] = wd[(o * 64 + c) * KK + k];
        wc1s[o * ROWP + c] = wc1[o * 64 + c];
    }
    __syncthreads();

    int ot = (t >> 4) * 4, cb = (t & 15) * 4;
    float a[4][4];
#pragma unroll
    for (int i = 0; i < 4; i++)
#pragma unroll
        for (int j = 0; j < 4; j++) a[i][j] = 0.f;
    for (int o = 0; o < 64; o++) {
        float wv_[4], sv_[4];
#pragma unroll
        for (int i = 0; i < 4; i++) wv_[i] = wc1s[(ot + i) * ROWP + o];
#pragma unroll
        for (int j = 0; j < 4; j++) sv_[j] = wdk[o * ROWP + cb + j];
#pragma unroll
        for (int i = 0; i < 4; i++)
#pragma unroll
            for (int j = 0; j < 4; j++) a[i][j] += wv_[i] * sv_[j];
    }
#pragma unroll
    for (int i = 0; i < 4; i++)
#pragma unroll
        for (int j = 0; j < 4; j++) {
            int o2 = ot + i, c = cb + j;
            int tt = o2 >> 4, m = o2 & 15;
            int kt = c >> 5, q = (c >> 3) & 3, jj = c & 7;
            int ln = q * 16 + m;
            wA[(k * 8 + tt * 2 + kt) * 512 + ln * 8 + jj] = (short)f2bf(a[i][j]);
        }
}

// ---------------------------------------------------------------------------
// k_trans: enc [c][p] -> encP [p][c]
// ---------------------------------------------------------------------------
__global__ __launch_bounds__(256) void k_trans(
    const float* __restrict__ enc, float* __restrict__ encP)
{
    __shared__ float s[64 * 65];
    int t = threadIdx.x;
    int base = blockIdx.x * 64;
#pragma unroll
    for (int r = 0; r < 16; r++) {
        int idx = t + r * 256;
        int p = idx & 63, c = idx >> 6;
        s[p * 65 + c] = enc[c * HWSZ + base + p];
    }
    __syncthreads();
#pragma unroll
    for (int r = 0; r < 16; r++) {
        int idx = t + r * 256;
        int c = idx & 63, p = idx >> 6;
        encP[(base + p) * 64 + c] = s[p * 65 + c];
    }
}

// ---------------------------------------------------------------------------
// k_deform: MFMA deformable conv, R8 bounce dataflow (measured-best),
// K split across 2 blocks/strip x 4 waves/block (6-7 taps per wave).
// Grid 4608: 18 blocks/CU demand vs 8 resident (LDS 19.4KB) -> residency
// pinned near max. Partials combined via device-scope atomicAdd into rev
// (zeroed by hipMemsetAsync before launch).
// ---------------------------------------------------------------------------
#define REDW 20   // reduction row stride (floats): 80B, 16B-aligned

__global__ __launch_bounds__(256) void k_deform(
    const float* __restrict__ encP, const float* __restrict__ off,
    const float* __restrict__ msk, const short* __restrict__ wA,
    float* __restrict__ rev)
{
    __shared__ __align__(16) short sm[4][16 * SROW];   // 9216 B bounce
    __shared__ __align__(16) float red[2 * 64 * REDW]; // 10240 B reduction

    int t = threadIdx.x;
    int lane = t & 63, w = t >> 6;
    int b = blockIdx.x;
    int s = b >> 1, h = b & 1;              // strip / K-half
    int xcd = s & 7, blk = s >> 3;          // 288 strips per xcd band
    int gy  = xcd * 24 + blk / 12;
    int gx0 = (blk % 12) * 16;

    int sp = lane >> 2, g = lane & 3;
    int sgx  = gx0 + sp;
    int gp_s = gy * WW + sgx;
    int n = lane & 15, q = lane >> 4;
    short* smw = &sm[w][0];

    f32x4 acc[4];
#pragma unroll
    for (int ot = 0; ot < 4; ot++) acc[ot] = (f32x4){0.f, 0.f, 0.f, 0.f};

    int kstart, kend;
    if (h == 0) { kstart = (w == 0) ? 0 : 7 + (w - 1) * 6;
                  kend   = kstart + ((w == 0) ? 7 : 6); }      // taps [0,25)
    else        { kstart = 25 + w * 6; kend = kstart + 6; }    // taps [25,49)

    float dy = off[(2 * kstart) * HWSZ + gp_s];
    float dx = off[(2 * kstart + 1) * HWSZ + gp_s];
    float mm = msk[kstart * HWSZ + gp_s];

#pragma unroll 1
    for (int k = kstart; k < kend; k++) {
        int ky = k / 7, kx = k % 7;
        float y = (float)(gy  - 3 + ky) + dy;
        float x = (float)(sgx - 3 + kx) + dx;
        float y0f = floorf(y), x0f = floorf(x);
        float wy = y - y0f, wx = x - x0f;
        int iy0 = (int)y0f, ix0 = (int)x0f;
        int iy1 = iy0 + 1, ix1 = ix0 + 1;
        bool vy0 = (iy0 >= 0) & (iy0 < HH);
        bool vy1 = (iy1 >= 0) & (iy1 < HH);
        bool vx0 = (ix0 >= 0) & (ix0 < WW);
        bool vx1 = (ix1 >= 0) & (ix1 < WW);
        int iy0c = min(max(iy0, 0), HH - 1), iy1c = min(max(iy1, 0), HH - 1);
        int ix0c = min(max(ix0, 0), WW - 1), ix1c = min(max(ix1, 0), WW - 1);
        float a00 = (vy0 & vx0) ? (1.f - wy) * (1.f - wx) * mm : 0.f;
        float a01 = (vy0 & vx1) ? (1.f - wy) * wx * mm : 0.f;
        float a10 = (vy1 & vx0) ? wy * (1.f - wx) * mm : 0.f;
        float a11 = (vy1 & vx1) ? wy * wx * mm : 0.f;

        const float4* p00 = (const float4*)(encP + (iy0c * WW + ix0c) * 64 + g * 16);
        const float4* p01 = (const float4*)(encP + (iy0c * WW + ix1c) * 64 + g * 16);
        const float4* p10 = (const float4*)(encP + (iy1c * WW + ix0c) * 64 + g * 16);
        const float4* p11 = (const float4*)(encP + (iy1c * WW + ix1c) * 64 + g * 16);
        float4 c00[4], c01[4], c10[4], c11[4];
#pragma unroll
        for (int i = 0; i < 4; i++) {
            c00[i] = p00[i]; c01[i] = p01[i];
            c10[i] = p10[i]; c11[i] = p11[i];
        }

        // prefetch next-tap offsets
        float dyn = 0.f, dxn = 0.f, mmn = 0.f;
        if (k + 1 < kend) {
            dyn = off[(2 * k + 2) * HWSZ + gp_s];
            dxn = off[(2 * k + 3) * HWSZ + gp_s];
            mmn = msk[(k + 1) * HWSZ + gp_s];
        }

        // A-frag loads (L2-hot, independent of samples)
        s16x8 af[8];
#pragma unroll
        for (int f = 0; f < 8; f++)
            af[f] = *(const s16x8*)&wA[(k * 8 + f) * 512 + lane * 8];

        // blend + pack bf16 + wave-private LDS bounce
        unsigned pk[8];
#pragma unroll
        for (int i = 0; i < 4; i++) {
            float f0 = a00 * c00[i].x + a01 * c01[i].x + a10 * c10[i].x + a11 * c11[i].x;
            float f1 = a00 * c00[i].y + a01 * c01[i].y + a10 * c10[i].y + a11 * c11[i].y;
            float f2 = a00 * c00[i].z + a01 * c01[i].z + a10 * c10[i].z + a11 * c11[i].z;
            float f3 = a00 * c00[i].w + a01 * c01[i].w + a10 * c10[i].w + a11 * c11[i].w;
            pk[2 * i]     = pkbf(f0, f1);
            pk[2 * i + 1] = pkbf(f2, f3);
        }
        *(uint4*)&smw[sp * SROW + g * 16]     = make_uint4(pk[0], pk[1], pk[2], pk[3]);
        *(uint4*)&smw[sp * SROW + g * 16 + 8] = make_uint4(pk[4], pk[5], pk[6], pk[7]);

        s16x8 b0 = *(const s16x8*)&smw[n * SROW +  0 + q * 8];
        s16x8 b1 = *(const s16x8*)&smw[n * SROW + 32 + q * 8];

#pragma unroll
        for (int ot = 0; ot < 4; ot++) {
            acc[ot] = __builtin_amdgcn_mfma_f32_16x16x32_bf16(af[ot * 2],     b0, acc[ot], 0, 0, 0);
            acc[ot] = __builtin_amdgcn_mfma_f32_16x16x32_bf16(af[ot * 2 + 1], b1, acc[ot], 0, 0, 0);
        }

        dy = dyn; dx = dxn; mm = mmn;
    }

    // two-phase tree reduction (2-slot buffer)
    if (w >= 2) {
        float* rp = &red[((w - 2) * 64 + lane) * REDW];
#pragma unroll
        for (int ot = 0; ot < 4; ot++)
            *(float4*)&rp[ot * 4] = make_float4(acc[ot][0], acc[ot][1], acc[ot][2], acc[ot][3]);
    }
    __syncthreads();
    if (w < 2) {
        const float* rp = &red[(w * 64 + lane) * REDW];
#pragma unroll
        for (int ot = 0; ot < 4; ot++) {
            float4 v = *(const float4*)&rp[ot * 4];
            acc[ot][0] += v.x; acc[ot][1] += v.y;
            acc[ot][2] += v.z; acc[ot][3] += v.w;
        }
    }
    __syncthreads();
    if (w == 1) {
        float* rp = &red[lane * REDW];
#pragma unroll
        for (int ot = 0; ot < 4; ot++)
            *(float4*)&rp[ot * 4] = make_float4(acc[ot][0], acc[ot][1], acc[ot][2], acc[ot][3]);
    }
    __syncthreads();
    if (w == 0) {
        const float* rp = &red[lane * REDW];
#pragma unroll
        for (int ot = 0; ot < 4; ot++) {
            float4 v = *(const float4*)&rp[ot * 4];
            acc[ot][0] += v.x; acc[ot][1] += v.y;
            acc[ot][2] += v.z; acc[ot][3] += v.w;
        }
        int gp_m = gy * WW + gx0 + n;
#pragma unroll
        for (int ot = 0; ot < 4; ot++)
#pragma unroll
            for (int r = 0; r < 4; r++)
                atomicAdd(&rev[gp_m * 64 + ot * 16 + q * 4 + r], acc[ot][r]);
    }
}

// ---------------------------------------------------------------------------
// k_fft: per 8x8 patch: proj_in via MFMA bf16, then circular conv (fp32).
// ---------------------------------------------------------------------------
__global__ __launch_bounds__(256) void k_fft(
    const float* __restrict__ encPg, const short* __restrict__ wpiA,
    const float* __restrict__ krT, float* __restrict__ e1)
{
    __shared__ __align__(16) short sbf[64 * SROW];   // bf16 enc [px][c]
    __shared__ __align__(16) float e0[64 * ROWP];    // fp32 [px][o]
    int t = threadIdx.x;
    int pbx = blockIdx.x % 24, pby = blockIdx.x / 24;
    int gx0 = pbx * 8, gy0 = pby * 8;

#pragma unroll
    for (int r = 0; r < 4; r++) {
        int idx = t + r * 256;
        int px = idx >> 4, g = idx & 15;
        int gy = gy0 + (px >> 3), gx = gx0 + (px & 7);
        float4 v = *(const float4*)&encPg[(gy * WW + gx) * 64 + g * 4];
        *(uint2*)&sbf[px * SROW + g * 4] = make_uint2(pkbf(v.x, v.y), pkbf(v.z, v.w));
    }
    __syncthreads();

    int lane = t & 63, w = t >> 6;
    int n = lane & 15, q = lane >> 4;
    s16x8 a0 = *(const s16x8*)&wpiA[(w * 2 + 0) * 512 + lane * 8];
    s16x8 a1 = *(const s16x8*)&wpiA[(w * 2 + 1) * 512 + lane * 8];
#pragma unroll
    for (int j = 0; j < 4; j++) {
        s16x8 b0 = *(const s16x8*)&sbf[(j * 16 + n) * SROW +  0 + q * 8];
        s16x8 b1 = *(const s16x8*)&sbf[(j * 16 + n) * SROW + 32 + q * 8];
        f32x4 acc = {0.f, 0.f, 0.f, 0.f};
        acc = __builtin_amdgcn_mfma_f32_16x16x32_bf16(a0, b0, acc, 0, 0, 0);
        acc = __builtin_amdgcn_mfma_f32_16x16x32_bf16(a1, b1, acc, 0, 0, 0);
#pragma unroll
        for (int r = 0; r < 4; r++)
            e0[(j * 16 + n) * ROWP + w * 16 + q * 4 + r] = acc[r];
    }
    __syncthreads();

    int o = t & 63;
    int yb = t >> 6;
#pragma unroll
    for (int yy = 0; yy < 2; yy++) {
        int y = yb + yy * 4;
        float outr[8];
#pragma unroll
        for (int x = 0; x < 8; x++) outr[x] = 0.f;
#pragma unroll
        for (int u = 0; u < 8; u++) {
            int ry = (y - u + 8) & 7;
            float row[8];
#pragma unroll
            for (int rx = 0; rx < 8; rx++)
                row[rx] = e0[(ry * 8 + rx) * ROWP + o];
#pragma unroll
            for (int v = 0; v < 8; v++) {
                float kv = krT[(u * 8 + v) * 64 + o];
#pragma unroll
                for (int x = 0; x < 8; x++)
                    outr[x] += kv * row[(x - v + 8) & 7];
            }
        }
        int gy = gy0 + y;
#pragma unroll
        for (int x = 0; x < 8; x++)
            e1[(gy * WW + gx0 + x) * 64 + o] = outr[x];
    }
}

// ---------------------------------------------------------------------------
// k_c3out: fused conv3x3(e1+rev) -> [.,dec] -> proj_out -> SimpleGate.
// ---------------------------------------------------------------------------
__global__ __launch_bounds__(256) void k_c3out(
    const float* __restrict__ e1, const float* __restrict__ rev,
    const short* __restrict__ w2A, const float* __restrict__ dec,
    const short* __restrict__ wpoA, float* __restrict__ out)
{
    __shared__ __align__(16) short sm[4][54 * C3ROW];  // per-wave: 3 rows x 18 px
    int t = threadIdx.x;
    int lane = t & 63, w = t >> 6;
    int b = blockIdx.x;
    int xcd = b & 7, blk = b >> 3;
    int gy  = xcd * 24 + blk / 3;
    int gx0 = (blk % 3) * 64 + w * 16;
    short* smw = &sm[w][0];
    int n = lane & 15, q = lane >> 4;

    for (int r = 0; r < 14; r++) {
        int u = lane + r * 64;
        if (u < 864) {
            int rp = u >> 4, g = u & 15;
            int row = rp / 18, pxl = rp - row * 18;
            int gyy = gy + row - 1, gxx = gx0 + pxl - 1;
            float4 v = make_float4(0.f, 0.f, 0.f, 0.f);
            if (gyy >= 0 && gyy < HH && gxx >= 0 && gxx < WW) {
                int gp = (gyy * WW + gxx) * 64 + g * 4;
                float4 va = *(const float4*)&e1[gp];
                float4 vb = *(const float4*)&rev[gp];
                v.x = va.x + vb.x; v.y = va.y + vb.y;
                v.z = va.z + vb.z; v.w = va.w + vb.w;
            }
            *(uint2*)&smw[rp * C3ROW + g * 4] = make_uint2(pkbf(v.x, v.y), pkbf(v.z, v.w));
        }
    }

    f32x4 acc[4];
#pragma unroll
    for (int ot = 0; ot < 4; ot++) acc[ot] = (f32x4){0.f, 0.f, 0.f, 0.f};

#pragma unroll 1
    for (int tap = 0; tap < 9; tap++) {
        int dy = tap / 3, dx = tap - dy * 3;
        int rp = dy * 18 + n + dx;
        s16x8 b0 = *(const s16x8*)&smw[rp * C3ROW +  0 + q * 8];
        s16x8 b1 = *(const s16x8*)&smw[rp * C3ROW + 32 + q * 8];
#pragma unroll
        for (int ot = 0; ot < 4; ot++) {
            s16x8 a0 = *(const s16x8*)&w2A[(tap * 8 + ot * 2 + 0) * 512 + lane * 8];
            s16x8 a1 = *(const s16x8*)&w2A[(tap * 8 + ot * 2 + 1) * 512 + lane * 8];
            acc[ot] = __builtin_amdgcn_mfma_f32_16x16x32_bf16(a0, b0, acc[ot], 0, 0, 0);
            acc[ot] = __builtin_amdgcn_mfma_f32_16x16x32_bf16(a1, b1, acc[ot], 0, 0, 0);
        }
    }

    // fused proj_out: stage e3 (C-layout regs) + dec into B-frag rows
#pragma unroll
    for (int ot = 0; ot < 4; ot++) {
        unsigned lo = pkbf(acc[ot][0], acc[ot][1]);
        unsigned hi = pkbf(acc[ot][2], acc[ot][3]);
        *(uint2*)&smw[n * OROW + ot * 16 + q * 4] = make_uint2(lo, hi);
    }
    {
        int gp = gy * WW + gx0 + n;
        unsigned pk[8];
#pragma unroll
        for (int i = 0; i < 8; i++) {
            float va = dec[(q * 16 + 2 * i)     * HWSZ + gp];
            float vb = dec[(q * 16 + 2 * i + 1) * HWSZ + gp];
            pk[i] = pkbf(va, vb);
        }
        *(uint4*)&smw[n * OROW + 64 + q * 16]     = make_uint4(pk[0], pk[1], pk[2], pk[3]);
        *(uint4*)&smw[n * OROW + 64 + q * 16 + 8] = make_uint4(pk[4], pk[5], pk[6], pk[7]);
    }

    f32x4 go[8];
#pragma unroll
    for (int ot = 0; ot < 8; ot++) go[ot] = (f32x4){0.f, 0.f, 0.f, 0.f};

#pragma unroll 1
    for (int kt = 0; kt < 4; kt++) {
        s16x8 bb = *(const s16x8*)&smw[n * OROW + kt * 32 + q * 8];
#pragma unroll
        for (int ot = 0; ot < 8; ot++) {
            s16x8 aa = *(const s16x8*)&wpoA[(ot * 4 + kt) * 512 + lane * 8];
            go[ot] = __builtin_amdgcn_mfma_f32_16x16x32_bf16(aa, bb, go[ot], 0, 0, 0);
        }
    }

    int gp = gy * WW + gx0 + n;
#pragma unroll
    for (int ot = 0; ot < 4; ot++)
#pragma unroll
        for (int r = 0; r < 4; r++)
            out[(ot * 16 + q * 4 + r) * HWSZ + gp] = go[ot][r] * go[ot + 4][r];
}

// ---------------------------------------------------------------------------
extern "C" void kernel_launch(void* const* d_in, const int* in_sizes, int n_in,
                              void* d_out, int out_size, void* d_ws, size_t ws_size,
                              hipStream_t stream)
{
    const float* enc  = (const float*)d_in[0];
    const float* dec  = (const float*)d_in[1];
    const float* ioff = (const float*)d_in[2];
    const float* iwt  = (const float*)d_in[3];
    const float* wpi  = (const float*)d_in[4];
    const float* fw   = (const float*)d_in[5];
    const float* wpo  = (const float*)d_in[6];
    const float* wd   = (const float*)d_in[7];
    const float* wc1  = (const float*)d_in[8];
    const float* wc2  = (const float*)d_in[9];
    float* out = (float*)d_out;
    float* ws  = (float*)d_ws;

    float* krT  = ws;                       //    4096
    float* rev  = ws + 4096;                // 2359296  [px][64]
    float* e1   = ws + 2363392;             // 2359296  [px][64]
    float* encP = ws + 4722688;             // 2359296  [px][64]
    short* wA   = (short*)(ws + 7081984);   // 200704 bf16
    short* w2A  = (short*)(ws + 7182336);   //  36864 bf16
    short* wpoA = (short*)(ws + 7200768);   //  16384 bf16
    short* wpiA = (short*)(ws + 7208960);   //   4096 bf16

    hipMemsetAsync(rev, 0, 2359296 * sizeof(float), stream);
    hipLaunchKernelGGL(k_prep,   dim3(49),   dim3(256), 0, stream,
                       fw, wd, wc2, wc1, wpo, wpi, krT, wA, w2A, wpoA, wpiA);
    hipLaunchKernelGGL(k_trans,  dim3(576),  dim3(256), 0, stream, enc, encP);
    hipLaunchKernelGGL(k_deform, dim3(4608), dim3(256), 0, stream, encP, ioff, iwt, wA, rev);
    hipLaunchKernelGGL(k_fft,    dim3(576),  dim3(256), 0, stream, encP, wpiA, krT, e1);
    hipLaunchKernelGGL(k_c3out,  dim3(576),  dim3(256), 0, stream, e1, rev, w2A, dec, wpoA, out);
}

// Round 11
// 216.495 us; speedup vs baseline: 1.7026x; 1.3671x over previous
//
#include <hip/hip_runtime.h>
#include <math.h>

#define CH    64
#define WW    192
#define HH    192
#define HWSZ  (192*192)
#define KK    49
#define ROWP  68   // padded fp32 LDS row (dwords)
#define SROW  72   // bf16 row stride in shorts (144B)
#define C3ROW 72   // conv3 staged px stride (shorts)
#define OROW  136  // k_out staged px stride (shorts, 128ch + 8 pad)

typedef __attribute__((ext_vector_type(8))) short s16x8;   // 8 bf16 = 4 VGPR
typedef __attribute__((ext_vector_type(4))) float f32x4;

__device__ __forceinline__ unsigned short f2bf(float f) {
    union { float f; unsigned u; } v; v.f = f;
    unsigned u = v.u + 0x7FFFu + ((v.u >> 16) & 1u);   // RNE
    return (unsigned short)(u >> 16);
}

// pack two floats to bf16x2 (round-half-up): 2 adds + 1 v_perm
__device__ __forceinline__ unsigned pkbf(float lo, float hi) {
    return __builtin_amdgcn_perm(__float_as_uint(hi) + 0x8000u,
                                 __float_as_uint(lo) + 0x8000u, 0x07060302u);
}

// ---------------------------------------------------------------------------
// k_prep (grid 49 x 256): krT + A-fragment packs (wA, w2A, wpoA, wpiA)
// ---------------------------------------------------------------------------
__device__ const float c_cos8[8] = {
    1.f, 0.70710678118654752f, 0.f, -0.70710678118654752f,
   -1.f, -0.70710678118654752f, 0.f, 0.70710678118654752f };

__global__ __launch_bounds__(256) void k_prep(
    const float* __restrict__ fw,   // [64,1,1,8,5]
    const float* __restrict__ wd,   // [64,64,7,7]
    const float* __restrict__ w2,   // [64,64,3,3]
    const float* __restrict__ wc1,  // [64,64,1,1]
    const float* __restrict__ wpo,  // [128,128]
    const float* __restrict__ wpi,  // [64,64]
    float* __restrict__ krT,        // [64 uv][64 c]
    short* __restrict__ wA,         // [49*8*512]
    short* __restrict__ w2A,        // [9*8*512]
    short* __restrict__ wpoA,       // [32*512]
    short* __restrict__ wpiA)       // [8*512]
{
    int tid = blockIdx.x * blockDim.x + threadIdx.x;
    int nt  = gridDim.x * blockDim.x;
    for (int t = tid; t < 64 * 64; t += nt) {
        int uv = t >> 6, c = t & 63;
        int u = uv >> 3, v = uv & 7;
        float acc = 0.f;
        for (int ky = 0; ky < 8; ky++)
            for (int kx = 0; kx < 8; kx++) {
                float wv = (kx <= 4) ? fw[c * 40 + ky * 5 + kx]
                                     : fw[c * 40 + ((8 - ky) & 7) * 5 + (8 - kx)];
                acc += wv * c_cos8[(ky * u + kx * v) & 7];
            }
        krT[uv * 64 + c] = acc * (1.f / 64.f);
    }
    for (int t = tid; t < 9 * 4096; t += nt) {
        int tap = t / 4096, rem = t & 4095;
        int o = rem >> 6, c = rem & 63;
        float v = w2[(o * 64 + c) * 9 + tap];
        int fi = tap * 8 + (o >> 4) * 2 + (c >> 5);
        int ln = ((c >> 3) & 3) * 16 + (o & 15);
        w2A[fi * 512 + ln * 8 + (c & 7)] = (short)f2bf(v);
    }
    for (int t = tid; t < 128 * 128; t += nt) {
        int o = t >> 7, c = t & 127;
        int fi = (o >> 4) * 4 + (c >> 5);
        int ln = ((c >> 3) & 3) * 16 + (o & 15);
        wpoA[fi * 512 + ln * 8 + (c & 7)] = (short)f2bf(wpo[t]);
    }
    for (int t = tid; t < 64 * 64; t += nt) {
        int o = t >> 6, c = t & 63;
        int fi = (o >> 4) * 2 + (c >> 5);
        int ln = ((c >> 3) & 3) * 16 + (o & 15);
        wpiA[fi * 512 + ln * 8 + (c & 7)] = (short)f2bf(wpi[t]);
    }

    // ---- fold wc1 @ wd + pack: one block per tap k ----
    __shared__ float wdk [64 * ROWP];
    __shared__ float wc1s[64 * ROWP];
    int k = blockIdx.x;
    int t = threadIdx.x;
#pragma unroll
    for (int r = 0; r < 16; r++) {
        int idx = t + r * 256;
        int o = idx >> 6, c = idx & 63;
        wdk [o * ROWP + c] = wd[(o * 64 + c) * KK + k];
        wc1s[o * ROWP + c] = wc1[o * 64 + c];
    }
    __syncthreads();

    int ot = (t >> 4) * 4, cb = (t & 15) * 4;
    float a[4][4];
#pragma unroll
    for (int i = 0; i < 4; i++)
#pragma unroll
        for (int j = 0; j < 4; j++) a[i][j] = 0.f;
    for (int o = 0; o < 64; o++) {
        float wv_[4], sv_[4];
#pragma unroll
        for (int i = 0; i < 4; i++) wv_[i] = wc1s[(ot + i) * ROWP + o];
#pragma unroll
        for (int j = 0; j < 4; j++) sv_[j] = wdk[o * ROWP + cb + j];
#pragma unroll
        for (int i = 0; i < 4; i++)
#pragma unroll
            for (int j = 0; j < 4; j++) a[i][j] += wv_[i] * sv_[j];
    }
#pragma unroll
    for (int i = 0; i < 4; i++)
#pragma unroll
        for (int j = 0; j < 4; j++) {
            int o2 = ot + i, c = cb + j;
            int tt = o2 >> 4, m = o2 & 15;
            int kt = c >> 5, q = (c >> 3) & 3, jj = c & 7;
            int ln = q * 16 + m;
            wA[(k * 8 + tt * 2 + kt) * 512 + ln * 8 + jj] = (short)f2bf(a[i][j]);
        }
}

// ---------------------------------------------------------------------------
// k_trans: enc [c][p] (fp32) -> encH [p][c] (bf16) -- halves gather bytes
// ---------------------------------------------------------------------------
__global__ __launch_bounds__(256) void k_trans(
    const float* __restrict__ enc, unsigned short* __restrict__ encH)
{
    __shared__ float s[64 * 65];
    int t = threadIdx.x;
    int base = blockIdx.x * 64;
#pragma unroll
    for (int r = 0; r < 16; r++) {
        int idx = t + r * 256;
        int p = idx & 63, c = idx >> 6;
        s[p * 65 + c] = enc[c * HWSZ + base + p];
    }
    __syncthreads();
#pragma unroll
    for (int r = 0; r < 8; r++) {
        int idx = t + r * 256;             // 2048 pair-units
        int pr = idx & 31, p = idx >> 5;   // pair 0..31, px 0..63
        ((unsigned*)encH)[(base + p) * 32 + pr] =
            pkbf(s[p * 65 + 2 * pr], s[p * 65 + 2 * pr + 1]);
    }
}

// ---------------------------------------------------------------------------
// k_deform: MFMA deformable conv, R8 structure (measured-best: grid 2304,
// 4-wave K-split 13/12/12/12, wave-private bounce, tree reduction), with
// bf16 gather: per corner 2x16B loads (8 scattered insts/tap vs 16),
// gather L2 bytes halved. Unpack bf16->fp32 (shl/and), blend fp32.
// ---------------------------------------------------------------------------
#define REDW 20   // reduction row stride (floats): 80B, 16B-aligned

__global__ __launch_bounds__(256) void k_deform(
    const unsigned short* __restrict__ encH, const float* __restrict__ off,
    const float* __restrict__ msk, const short* __restrict__ wA,
    float* __restrict__ rev)
{
    __shared__ __align__(16) short sm[4][16 * SROW];   // 9216 B bounce
    __shared__ __align__(16) float red[2 * 64 * REDW]; // 10240 B reduction

    int t = threadIdx.x;
    int lane = t & 63, w = t >> 6;
    int b = blockIdx.x;
    int xcd = b & 7, blk = b >> 3;          // 288 strips per xcd band
    int gy  = xcd * 24 + blk / 12;
    int gx0 = (blk % 12) * 16;

    int sp = lane >> 2, g = lane & 3;
    int sgx  = gx0 + sp;
    int gp_s = gy * WW + sgx;
    int n = lane & 15, q = lane >> 4;
    short* smw = &sm[w][0];

    f32x4 acc[4];
#pragma unroll
    for (int ot = 0; ot < 4; ot++) acc[ot] = (f32x4){0.f, 0.f, 0.f, 0.f};

    int kstart = (w == 0) ? 0 : 13 + (w - 1) * 12;
    int kend   = (w == 0) ? 13 : kstart + 12;

    float dy = off[(2 * kstart) * HWSZ + gp_s];
    float dx = off[(2 * kstart + 1) * HWSZ + gp_s];
    float mm = msk[kstart * HWSZ + gp_s];

#pragma unroll 1
    for (int k = kstart; k < kend; k++) {
        int ky = k / 7, kx = k % 7;
        float y = (float)(gy  - 3 + ky) + dy;
        float x = (float)(sgx - 3 + kx) + dx;
        float y0f = floorf(y), x0f = floorf(x);
        float wy = y - y0f, wx = x - x0f;
        int iy0 = (int)y0f, ix0 = (int)x0f;
        int iy1 = iy0 + 1, ix1 = ix0 + 1;
        bool vy0 = (iy0 >= 0) & (iy0 < HH);
        bool vy1 = (iy1 >= 0) & (iy1 < HH);
        bool vx0 = (ix0 >= 0) & (ix0 < WW);
        bool vx1 = (ix1 >= 0) & (ix1 < WW);
        int iy0c = min(max(iy0, 0), HH - 1), iy1c = min(max(iy1, 0), HH - 1);
        int ix0c = min(max(ix0, 0), WW - 1), ix1c = min(max(ix1, 0), WW - 1);
        float a00 = (vy0 & vx0) ? (1.f - wy) * (1.f - wx) * mm : 0.f;
        float a01 = (vy0 & vx1) ? (1.f - wy) * wx * mm : 0.f;
        float a10 = (vy1 & vx0) ? wy * (1.f - wx) * mm : 0.f;
        float a11 = (vy1 & vx1) ? wy * wx * mm : 0.f;

        // bf16 corners: 16 ch per lane = 2x16B per corner
        const unsigned short* b00p = encH + (iy0c * WW + ix0c) * 64 + g * 16;
        const unsigned short* b01p = encH + (iy0c * WW + ix1c) * 64 + g * 16;
        const unsigned short* b10p = encH + (iy1c * WW + ix0c) * 64 + g * 16;
        const unsigned short* b11p = encH + (iy1c * WW + ix1c) * 64 + g * 16;
        uint4 u00[2], u01[2], u10[2], u11[2];
        u00[0] = *(const uint4*)b00p;  u00[1] = *(const uint4*)(b00p + 8);
        u01[0] = *(const uint4*)b01p;  u01[1] = *(const uint4*)(b01p + 8);
        u10[0] = *(const uint4*)b10p;  u10[1] = *(const uint4*)(b10p + 8);
        u11[0] = *(const uint4*)b11p;  u11[1] = *(const uint4*)(b11p + 8);

        // prefetch next-tap offsets
        float dyn = 0.f, dxn = 0.f, mmn = 0.f;
        if (k + 1 < kend) {
            dyn = off[(2 * k + 2) * HWSZ + gp_s];
            dxn = off[(2 * k + 3) * HWSZ + gp_s];
            mmn = msk[(k + 1) * HWSZ + gp_s];
        }

        // A-frag loads (L2-hot, independent of samples)
        s16x8 af[8];
#pragma unroll
        for (int f = 0; f < 8; f++)
            af[f] = *(const s16x8*)&wA[(k * 8 + f) * 512 + lane * 8];

        // unpack + blend (fp32) + pack + wave-private LDS bounce
        float res[16];
#pragma unroll
        for (int j = 0; j < 16; j++) res[j] = 0.f;
        {
            const uint4* cs[4] = {u00, u01, u10, u11};
            float       aw[4] = {a00, a01, a10, a11};
#pragma unroll
            for (int cix = 0; cix < 4; cix++) {
                unsigned uu[8] = {cs[cix][0].x, cs[cix][0].y, cs[cix][0].z, cs[cix][0].w,
                                  cs[cix][1].x, cs[cix][1].y, cs[cix][1].z, cs[cix][1].w};
                float a = aw[cix];
#pragma unroll
                for (int j = 0; j < 8; j++) {
                    res[2 * j]     += a * __uint_as_float(uu[j] << 16);
                    res[2 * j + 1] += a * __uint_as_float(uu[j] & 0xffff0000u);
                }
            }
        }
        unsigned pk[8];
#pragma unroll
        for (int j = 0; j < 8; j++) pk[j] = pkbf(res[2 * j], res[2 * j + 1]);
        *(uint4*)&smw[sp * SROW + g * 16]     = make_uint4(pk[0], pk[1], pk[2], pk[3]);
        *(uint4*)&smw[sp * SROW + g * 16 + 8] = make_uint4(pk[4], pk[5], pk[6], pk[7]);

        s16x8 b0 = *(const s16x8*)&smw[n * SROW +  0 + q * 8];
        s16x8 b1 = *(const s16x8*)&smw[n * SROW + 32 + q * 8];

#pragma unroll
        for (int ot = 0; ot < 4; ot++) {
            acc[ot] = __builtin_amdgcn_mfma_f32_16x16x32_bf16(af[ot * 2],     b0, acc[ot], 0, 0, 0);
            acc[ot] = __builtin_amdgcn_mfma_f32_16x16x32_bf16(af[ot * 2 + 1], b1, acc[ot], 0, 0, 0);
        }

        dy = dyn; dx = dxn; mm = mmn;
    }

    // two-phase tree reduction (2-slot buffer)
    if (w >= 2) {
        float* rp = &red[((w - 2) * 64 + lane) * REDW];
#pragma unroll
        for (int ot = 0; ot < 4; ot++)
            *(float4*)&rp[ot * 4] = make_float4(acc[ot][0], acc[ot][1], acc[ot][2], acc[ot][3]);
    }
    __syncthreads();
    if (w < 2) {
        const float* rp = &red[(w * 64 + lane) * REDW];
#pragma unroll
        for (int ot = 0; ot < 4; ot++) {
            float4 v = *(const float4*)&rp[ot * 4];
            acc[ot][0] += v.x; acc[ot][1] += v.y;
            acc[ot][2] += v.z; acc[ot][3] += v.w;
        }
    }
    __syncthreads();
    if (w == 1) {
        float* rp = &red[lane * REDW];
#pragma unroll
        for (int ot = 0; ot < 4; ot++)
            *(float4*)&rp[ot * 4] = make_float4(acc[ot][0], acc[ot][1], acc[ot][2], acc[ot][3]);
    }
    __syncthreads();
    if (w == 0) {
        const float* rp = &red[lane * REDW];
#pragma unroll
        for (int ot = 0; ot < 4; ot++) {
            float4 v = *(const float4*)&rp[ot * 4];
            acc[ot][0] += v.x; acc[ot][1] += v.y;
            acc[ot][2] += v.z; acc[ot][3] += v.w;
        }
        int gp_m = gy * WW + gx0 + n;
#pragma unroll
        for (int ot = 0; ot < 4; ot++) {
            float4 rv = make_float4(acc[ot][0], acc[ot][1], acc[ot][2], acc[ot][3]);
            *(float4*)&rev[gp_m * 64 + ot * 16 + q * 4] = rv;
        }
    }
}

// ---------------------------------------------------------------------------
// k_fft: per 8x8 patch: proj_in via MFMA bf16, then circular conv (fp32).
// Stages straight from bf16 encH (plain 16B copies, no packing).
// ---------------------------------------------------------------------------
__global__ __launch_bounds__(256) void k_fft(
    const unsigned short* __restrict__ encH, const short* __restrict__ wpiA,
    const float* __restrict__ krT, float* __restrict__ e1)
{
    __shared__ __align__(16) short sbf[64 * SROW];   // bf16 enc [px][c]
    __shared__ __align__(16) float e0[64 * ROWP];    // fp32 [px][o]
    int t = threadIdx.x;
    int pbx = blockIdx.x % 24, pby = blockIdx.x / 24;
    int gx0 = pbx * 8, gy0 = pby * 8;

#pragma unroll
    for (int r = 0; r < 2; r++) {
        int idx = t + r * 256;             // 512 x 8-ch units
        int px = idx >> 3, g8 = idx & 7;
        int gy = gy0 + (px >> 3), gx = gx0 + (px & 7);
        *(uint4*)&sbf[px * SROW + g8 * 8] =
            *(const uint4*)&encH[(gy * WW + gx) * 64 + g8 * 8];
    }
    __syncthreads();

    int lane = t & 63, w = t >> 6;
    int n = lane & 15, q = lane >> 4;
    s16x8 a0 = *(const s16x8*)&wpiA[(w * 2 + 0) * 512 + lane * 8];
    s16x8 a1 = *(const s16x8*)&wpiA[(w * 2 + 1) * 512 + lane * 8];
#pragma unroll
    for (int j = 0; j < 4; j++) {
        s16x8 b0 = *(const s16x8*)&sbf[(j * 16 + n) * SROW +  0 + q * 8];
        s16x8 b1 = *(const s16x8*)&sbf[(j * 16 + n) * SROW + 32 + q * 8];
        f32x4 acc = {0.f, 0.f, 0.f, 0.f};
        acc = __builtin_amdgcn_mfma_f32_16x16x32_bf16(a0, b0, acc, 0, 0, 0);
        acc = __builtin_amdgcn_mfma_f32_16x16x32_bf16(a1, b1, acc, 0, 0, 0);
#pragma unroll
        for (int r = 0; r < 4; r++)
            e0[(j * 16 + n) * ROWP + w * 16 + q * 4 + r] = acc[r];
    }
    __syncthreads();

    int o = t & 63;
    int yb = t >> 6;
#pragma unroll
    for (int yy = 0; yy < 2; yy++) {
        int y = yb + yy * 4;
        float outr[8];
#pragma unroll
        for (int x = 0; x < 8; x++) outr[x] = 0.f;
#pragma unroll
        for (int u = 0; u < 8; u++) {
            int ry = (y - u + 8) & 7;
            float row[8];
#pragma unroll
            for (int rx = 0; rx < 8; rx++)
                row[rx] = e0[(ry * 8 + rx) * ROWP + o];
#pragma unroll
            for (int v = 0; v < 8; v++) {
                float kv = krT[(u * 8 + v) * 64 + o];
#pragma unroll
                for (int x = 0; x < 8; x++)
                    outr[x] += kv * row[(x - v + 8) & 7];
            }
        }
        int gy = gy0 + y;
#pragma unroll
        for (int x = 0; x < 8; x++)
            e1[(gy * WW + gx0 + x) * 64 + o] = outr[x];
    }
}

// ---------------------------------------------------------------------------
// k_c3out: fused conv3x3(e1+rev) -> [.,dec] -> proj_out -> SimpleGate.
// ---------------------------------------------------------------------------
__global__ __launch_bounds__(256) void k_c3out(
    const float* __restrict__ e1, const float* __restrict__ rev,
    const short* __restrict__ w2A, const float* __restrict__ dec,
    const short* __restrict__ wpoA, float* __restrict__ out)
{
    __shared__ __align__(16) short sm[4][54 * C3ROW];  // per-wave: 3 rows x 18 px
    int t = threadIdx.x;
    int lane = t & 63, w = t >> 6;
    int b = blockIdx.x;
    int xcd = b & 7, blk = b >> 3;
    int gy  = xcd * 24 + blk / 3;
    int gx0 = (blk % 3) * 64 + w * 16;
    short* smw = &sm[w][0];
    int n = lane & 15, q = lane >> 4;

    for (int r = 0; r < 14; r++) {
        int u = lane + r * 64;
        if (u < 864) {
            int rp = u >> 4, g = u & 15;
            int row = rp / 18, pxl = rp - row * 18;
            int gyy = gy + row - 1, gxx = gx0 + pxl - 1;
            float4 v = make_float4(0.f, 0.f, 0.f, 0.f);
            if (gyy >= 0 && gyy < HH && gxx >= 0 && gxx < WW) {
                int gp = (gyy * WW + gxx) * 64 + g * 4;
                float4 va = *(const float4*)&e1[gp];
                float4 vb = *(const float4*)&rev[gp];
                v.x = va.x + vb.x; v.y = va.y + vb.y;
                v.z = va.z + vb.z; v.w = va.w + vb.w;
            }
            *(uint2*)&smw[rp * C3ROW + g * 4] = make_uint2(pkbf(v.x, v.y), pkbf(v.z, v.w));
        }
    }

    f32x4 acc[4];
#pragma unroll
    for (int ot = 0; ot < 4; ot++) acc[ot] = (f32x4){0.f, 0.f, 0.f, 0.f};

#pragma unroll 1
    for (int tap = 0; tap < 9; tap++) {
        int dy = tap / 3, dx = tap - dy * 3;
        int rp = dy * 18 + n + dx;
        s16x8 b0 = *(const s16x8*)&smw[rp * C3ROW +  0 + q * 8];
        s16x8 b1 = *(const s16x8*)&smw[rp * C3ROW + 32 + q * 8];
#pragma unroll
        for (int ot = 0; ot < 4; ot++) {
            s16x8 a0 = *(const s16x8*)&w2A[(tap * 8 + ot * 2 + 0) * 512 + lane * 8];
            s16x8 a1 = *(const s16x8*)&w2A[(tap * 8 + ot * 2 + 1) * 512 + lane * 8];
            acc[ot] = __builtin_amdgcn_mfma_f32_16x16x32_bf16(a0, b0, acc[ot], 0, 0, 0);
            acc[ot] = __builtin_amdgcn_mfma_f32_16x16x32_bf16(a1, b1, acc[ot], 0, 0, 0);
        }
    }

    // fused proj_out: stage e3 (C-layout regs) + dec into B-frag rows
#pragma unroll
    for (int ot = 0; ot < 4; ot++) {
        unsigned lo = pkbf(acc[ot][0], acc[ot][1]);
        unsigned hi = pkbf(acc[ot][2], acc[ot][3]);
        *(uint2*)&smw[n * OROW + ot * 16 + q * 4] = make_uint2(lo, hi);
    }
    {
        int gp = gy * WW + gx0 + n;
        unsigned pk[8];
#pragma unroll
        for (int i = 0; i < 8; i++) {
            float va = dec[(q * 16 + 2 * i)     * HWSZ + gp];
            float vb = dec[(q * 16 + 2 * i + 1) * HWSZ + gp];
            pk[i] = pkbf(va, vb);
        }
        *(uint4*)&smw[n * OROW + 64 + q * 16]     = make_uint4(pk[0], pk[1], pk[2], pk[3]);
        *(uint4*)&smw[n * OROW + 64 + q * 16 + 8] = make_uint4(pk[4], pk[5], pk[6], pk[7]);
    }

    f32x4 go[8];
#pragma unroll
    for (int ot = 0; ot < 8; ot++) go[ot] = (f32x4){0.f, 0.f, 0.f, 0.f};

#pragma unroll 1
    for (int kt = 0; kt < 4; kt++) {
        s16x8 bb = *(const s16x8*)&smw[n * OROW + kt * 32 + q * 8];
#pragma unroll
        for (int ot = 0; ot < 8; ot++) {
            s16x8 aa = *(const s16x8*)&wpoA[(ot * 4 + kt) * 512 + lane * 8];
            go[ot] = __builtin_amdgcn_mfma_f32_16x16x32_bf16(aa, bb, go[ot], 0, 0, 0);
        }
    }

    int gp = gy * WW + gx0 + n;
#pragma unroll
    for (int ot = 0; ot < 4; ot++)
#pragma unroll
        for (int r = 0; r < 4; r++)
            out[(ot * 16 + q * 4 + r) * HWSZ + gp] = go[ot][r] * go[ot + 4][r];
}

// ---------------------------------------------------------------------------
extern "C" void kernel_launch(void* const* d_in, const int* in_sizes, int n_in,
                              void* d_out, int out_size, void* d_ws, size_t ws_size,
                              hipStream_t stream)
{
    const float* enc  = (const float*)d_in[0];
    const float* dec  = (const float*)d_in[1];
    const float* ioff = (const float*)d_in[2];
    const float* iwt  = (const float*)d_in[3];
    const float* wpi  = (const float*)d_in[4];
    const float* fw   = (const float*)d_in[5];
    const float* wpo  = (const float*)d_in[6];
    const float* wd   = (const float*)d_in[7];
    const float* wc1  = (const float*)d_in[8];
    const float* wc2  = (const float*)d_in[9];
    float* out = (float*)d_out;
    float* ws  = (float*)d_ws;

    float*          krT  = ws;                           //    4096
    float*          rev  = ws + 4096;                    // 2359296  [px][64]
    float*          e1   = ws + 2363392;                 // 2359296  [px][64]
    unsigned short* encH = (unsigned short*)(ws + 4722688); // 2359296 bf16 (1179648 fl)
    short*          wA   = (short*)(ws + 5902336);       // 200704 bf16
    short*          w2A  = (short*)(ws + 6002688);       //  36864 bf16
    short*          wpoA = (short*)(ws + 6021120);       //  16384 bf16
    short*          wpiA = (short*)(ws + 6029312);       //   4096 bf16

    hipLaunchKernelGGL(k_prep,   dim3(49),   dim3(256), 0, stream,
                       fw, wd, wc2, wc1, wpo, wpi, krT, wA, w2A, wpoA, wpiA);
    hipLaunchKernelGGL(k_trans,  dim3(576),  dim3(256), 0, stream, enc, encH);
    hipLaunchKernelGGL(k_deform, dim3(2304), dim3(256), 0, stream, encH, ioff, iwt, wA, rev);
    hipLaunchKernelGGL(k_fft,    dim3(576),  dim3(256), 0, stream, encH, wpiA, krT, e1);
    hipLaunchKernelGGL(k_c3out,  dim3(576),  dim3(256), 0, stream, e1, rev, w2A, dec, wpoA, out);
}